// Round 10
// baseline (152.598 us; speedup 1.0000x reference)
//
#include <hip/hip_runtime.h>

// LePEAttention idx=0 on MI355X — R10 (= R9 resubmitted; R9 was an infra failure,
// "MI355X container failed twice" — kernel never ran. Virtual-slot math re-audited:
// map bijective, pairs dword-contiguous, banks 2-way/free, PV permutation-invariant).
// Design: S^T = MFMA(kf, qf) so lane(quad,col) holds, for query col, s0-keys 4q..+3
// and s1-keys 16+4q..+3. Virtual key order v=(kk&12)*2+((kk>>4)&1)*4+(kk&3) makes the
// in-lane pack of exp2 results the PV A-fragment directly; V staged at virtual slots
// (store-side index math only). No P LDS, no shuffles, no fences.
// qkv f32 [3,8,4096,128]; out f32 [8,4096,128]. 64 windows of S=512; 256 (win,head)
// pairs x 4 q-splits(128q); block 256 = 4 waves x 32 q. mfma_f32_16x16x32_bf16.

typedef __attribute__((ext_vector_type(8))) short bf16x8;
typedef __attribute__((ext_vector_type(4))) float f32x4;
typedef __attribute__((ext_vector_type(4))) int   i32x4;

#define MFMA16(a, b, c) __builtin_amdgcn_mfma_f32_16x16x32_bf16(a, b, c, 0, 0, 0)

__device__ __forceinline__ unsigned rne(float f) {           // bf16(rne) in hi16
    union { float f; unsigned u; } v; v.f = f;
    return v.u + 0x7fffu + ((v.u >> 16) & 1u);
}
__device__ __forceinline__ short f2b(float f) { return (short)(rne(f) >> 16); }
__device__ __forceinline__ unsigned pkhi(unsigned lo, unsigned hi) {
    // dword = hi16(lo) | hi16(hi)<<16  (v_perm: sel bytes 0-3 from src1, 4-7 from src0)
    return __builtin_amdgcn_perm(hi, lo, 0x07060302u);
}

__global__ __launch_bounds__(256, 4)
void lepe_attn_r10(const float* __restrict__ qkv, float* __restrict__ out)
{
    __shared__ __align__(16) short    Ks[256 * 32];    // 16 KB, XOR-swizzled 16B blocks
    __shared__ __align__(16) unsigned Vt32[32 * 132];  // 16.5 KB: [dim][pair-slot], VIRTUAL key order

    const int tid  = threadIdx.x;
    const int wave = tid >> 6;
    const int lane = tid & 63;
    const int col  = lane & 15;
    const int quad = lane >> 4;

    const int blk  = blockIdx.x;
    const int pair = blk >> 2;
    const int qsp  = blk & 3;
    const int wi   = pair >> 2;
    const int hd   = pair & 3;
    const int b    = wi >> 3;
    const int wb   = wi & 7;
    const int chead = hd * 32;

    const size_t baseQ = (size_t)b * 524288;
    const size_t baseK = baseQ + 8u * 524288;
    const size_t baseV = baseQ + 16u * 524288;

    // ---- Q frags (B operand: B[n=q=col][k=d=quad*8+j]), prescaled by SCALE*log2e
    const int q0 = qsp * 128 + wave * 32;
    const float QS   = 0.17677669529663687f * 1.4426950408889634f;
    const float MAXB = 32.0f;
    bf16x8 qf[2];
#pragma unroll
    for (int t = 0; t < 2; ++t) {
        int q  = q0 + t * 16 + col;
        int lq = (q >> 3) * 64 + wb * 8 + (q & 7);
        const float* qp = qkv + baseQ + (size_t)lq * 128 + chead + quad * 8;
        f32x4 qa = *(const f32x4*)qp;
        f32x4 qb = *(const f32x4*)(qp + 4);
        bf16x8 qs;
#pragma unroll
        for (int j = 0; j < 4; ++j) { qs[j] = f2b(qa[j] * QS); qs[j + 4] = f2b(qb[j] * QS); }
        qf[t] = qs;
    }

    f32x4 o[2][2];
    float lsum[2] = {0.0f, 0.0f};
#pragma unroll
    for (int t = 0; t < 2; ++t) { o[t][0] = (f32x4)0.0f; o[t][1] = (f32x4)0.0f; }

    for (int stage = 0; stage < 2; ++stage) {
        if (stage) __syncthreads();
        const int keybase = stage * 256;

        // ---- K staging: row-major bf16, XOR-swizzled 16B blocks
#pragma unroll
        for (int i = 0; i < 4; ++i) {
            int chunk = i * 256 + tid;
            int row   = chunk >> 2;
            int part  = chunk & 3;
            int gk    = keybase + row;
            int lk    = (gk >> 3) * 64 + wb * 8 + (gk & 7);
            const float* kp = qkv + baseK + (size_t)lk * 128 + chead + part * 8;
            f32x4 k0 = *(const f32x4*)kp;
            f32x4 k1 = *(const f32x4*)(kp + 4);
            bf16x8 kv;
#pragma unroll
            for (int j = 0; j < 4; ++j) { kv[j] = f2b(k0[j]); kv[j + 4] = f2b(k1[j]); }
            *(bf16x8*)&Ks[row * 32 + ((part ^ ((row >> 1) & 3)) << 3)] = kv;
        }
        // ---- V staging: transposed, pair-packed, written at VIRTUAL slots.
        // v = (kk&12)*2 + ((kk>>4)&1)*4 + (kk&3); dword slot = v>>1 within the
        // 16-dword group; pairs (2p,2p+1) stay contiguous (bit0 preserved).
        {
            int p    = tid >> 1;                 // pair index 0..127 (orig keys 2p,2p+1)
            int half = tid & 1;                  // dim half
            int k0g  = keybase + 2 * p;
            int l0   = (k0g >> 3) * 64 + wb * 8 + (k0g & 7);   // key 2p+1 = row l0+1
            const float* va = qkv + baseV + (size_t)l0 * 128 + chead + half * 16;
            const float* vb = va + 128;
            int kk   = (p & 15) * 2;             // orig even key within its 32-group
            int slot = (p >> 4) * 16 + ((kk & 12) + ((kk >> 4) & 1) * 2 + ((kk & 3) >> 1));
            f32x4 a[4], bb[4];
#pragma unroll
            for (int j = 0; j < 4; ++j) { a[j] = *(const f32x4*)(va + 4 * j); bb[j] = *(const f32x4*)(vb + 4 * j); }
#pragma unroll
            for (int j = 0; j < 4; ++j)
#pragma unroll
                for (int e = 0; e < 4; ++e) {
                    int dim = half * 16 + j * 4 + e;
                    Vt32[dim * 132 + slot] = pkhi(rne(a[j][e]), rne(bb[j][e]));
                }
        }
        __syncthreads();

        for (int kb = 0; kb < 256; kb += 32) {
            int r0 = kb + col, r1 = kb + col + 16;
            bf16x8 kf0 = *(const bf16x8*)&Ks[r0 * 32 + ((quad ^ ((r0 >> 1) & 3)) << 3)];
            bf16x8 kf1 = *(const bf16x8*)&Ks[r1 * 32 + ((quad ^ ((r1 >> 1) & 3)) << 3)];
            const short* Vts = (const short*)Vt32;
            // V frags in virtual order: lane(quad,col) reads virtual keys kb+quad*8..+7
            bf16x8 vf0 = *(const bf16x8*)&Vts[col * 264 + kb + quad * 8];
            bf16x8 vf1 = *(const bf16x8*)&Vts[(col + 16) * 264 + kb + quad * 8];

#pragma unroll
            for (int t = 0; t < 2; ++t) {
                // S^T tiles: D[row=key][col=q]  (A = K-frag, B = Q-frag)
                f32x4 s0 = MFMA16(kf0, qf[t], (f32x4)0.0f);   // orig keys kb+quad*4+r
                f32x4 s1 = MFMA16(kf1, qf[t], (f32x4)0.0f);   // orig keys kb+16+quad*4+r
                float p0[4], p1[4];
#pragma unroll
                for (int r = 0; r < 4; ++r) {
                    p0[r] = __builtin_amdgcn_exp2f(s0[r] - MAXB);
                    p1[r] = __builtin_amdgcn_exp2f(s1[r] - MAXB);
                }
                lsum[t] += (p0[0] + p0[1]) + (p0[2] + p0[3]) + (p1[0] + p1[1]) + (p1[2] + p1[3]);
                // In-lane A-frag (virtual keys quad*8+j for query col): no shuffles.
                i32x4 fr;
                fr[0] = (int)pkhi(rne(p0[0]), rne(p0[1]));   // v keys q*8+0,1
                fr[1] = (int)pkhi(rne(p0[2]), rne(p0[3]));   // v keys q*8+2,3
                fr[2] = (int)pkhi(rne(p1[0]), rne(p1[1]));   // v keys q*8+4,5
                fr[3] = (int)pkhi(rne(p1[2]), rne(p1[3]));   // v keys q*8+6,7
                bf16x8 pf = __builtin_bit_cast(bf16x8, fr);
                o[t][0] = MFMA16(pf, vf0, o[t][0]);   // D[row=q][col=dim]
                o[t][1] = MFMA16(pf, vf1, o[t][1]);
            }
        }
    }

    // ---- epilogue: lsum is per (t, query=col) spread over quads; butterfly, normalize
    const size_t baseO = (size_t)b * 524288;
#pragma unroll
    for (int t = 0; t < 2; ++t) {
        float ls = lsum[t];
        ls += __shfl_xor(ls, 16, 64);
        ls += __shfl_xor(ls, 32, 64);   // lanes {col,col+16,col+32,col+48}: full sum for query col
#pragma unroll
        for (int r = 0; r < 4; ++r) {
            float inv = 1.0f / __shfl(ls, quad * 4 + r, 64);  // lane quad*4+r holds query quad*4+r
            int q  = q0 + t * 16 + quad * 4 + r;
            int lq = (q >> 3) * 64 + wb * 8 + (q & 7);
            float* orow = out + baseO + (size_t)lq * 128 + chead;
            orow[col]      = o[t][0][r] * inv;
            orow[col + 16] = o[t][1][r] * inv;
        }
    }
}

extern "C" void kernel_launch(void* const* d_in, const int* in_sizes, int n_in,
                              void* d_out, int out_size, void* d_ws, size_t ws_size,
                              hipStream_t stream) {
    const float* qkv = (const float*)d_in[0];
    float* out = (float*)d_out;
    lepe_attn_r10<<<dim3(1024), dim3(256), 0, stream>>>(qkv, out);
}